// Round 1
// baseline (3243.217 us; speedup 1.0000x reference)
//
#include <hip/hip_runtime.h>
#include <math.h>

#define BB 32
#define SS 1024
#define DD 512
#define BSROWS (BB*SS)   // 32768 rows

// ---------------- K1: embedding gather + layernorm ----------------
// one block per (b,s) row; 256 threads x float2 = 512 elements
__global__ __launch_bounds__(256) void k_embed_ln(
    const int* __restrict__ inp, const float* __restrict__ wemb,
    const float* __restrict__ pemb, const float* __restrict__ gamma,
    const float* __restrict__ beta, float* __restrict__ X)
{
  int row = blockIdx.x;            // 0..32767
  int s   = row & (SS - 1);        // position
  int tid = threadIdx.x;
  int tok = inp[row];
  float2 w = ((const float2*)(wemb + (size_t)tok * DD))[tid];
  float2 p = ((const float2*)(pemb + (size_t)s   * DD))[tid];
  float ex = w.x + p.x, ey = w.y + p.y;
  float sum = ex + ey;
  float ssq = ex*ex + ey*ey;
  #pragma unroll
  for (int off = 32; off > 0; off >>= 1) {
    sum += __shfl_down(sum, off, 64);
    ssq += __shfl_down(ssq, off, 64);
  }
  __shared__ float red[10];
  int wv = tid >> 6, ln = tid & 63;
  if (ln == 0) { red[wv] = sum; red[4 + wv] = ssq; }
  __syncthreads();
  if (tid == 0) {
    float s4 = red[0] + red[1] + red[2] + red[3];
    float q4 = red[4] + red[5] + red[6] + red[7];
    float mean = s4 * (1.0f / DD);
    float var  = q4 * (1.0f / DD) - mean * mean;   // jnp.var: biased
    red[8] = mean;
    red[9] = rsqrtf(var + 1e-5f);
  }
  __syncthreads();
  float mean = red[8], rstd = red[9];
  float2 g  = ((const float2*)gamma)[tid];
  float2 bt = ((const float2*)beta)[tid];
  float2 o;
  o.x = (ex - mean) * rstd * g.x + bt.x;
  o.y = (ey - mean) * rstd * g.y + bt.y;
  ((float2*)(X + (size_t)row * DD))[tid] = o;
}

// ---------------- K2: fused QKV projection GEMM (fp32) ----------------
// C = X * W for W in {Wq,Wk,Wv}; X tile loaded once, reused 3x.
// BM=64, BN=64, BK=16, 256 threads, 4x4 micro-tile per output.
__global__ __launch_bounds__(256) void k_qkv(
    const float* __restrict__ X, const float* __restrict__ Wq,
    const float* __restrict__ Wk, const float* __restrict__ Wv,
    float* __restrict__ Qo, float* __restrict__ Ko, float* __restrict__ Vo)
{
  __shared__ float As[16][68];                    // X^T tile, padded
  __shared__ float Bq[16][64], Bk[16][64], Bv[16][64];
  int tid = threadIdx.x;
  int n0 = blockIdx.x * 64;
  int m0 = blockIdx.y * 64;
  int lm = tid >> 2, lk = (tid & 3) * 4;          // X-tile load map
  int wk = tid >> 4, wn = (tid & 15) * 4;         // W-tile load map
  int tm = (tid >> 4) * 4, tn = (tid & 15) * 4;   // compute map
  float aq[4][4] = {{0}}, ak[4][4] = {{0}}, av[4][4] = {{0}};
  for (int k0 = 0; k0 < DD; k0 += 16) {
    __syncthreads();
    float4 xa = *(const float4*)&X[(size_t)(m0 + lm) * DD + k0 + lk];
    As[lk + 0][lm] = xa.x; As[lk + 1][lm] = xa.y;
    As[lk + 2][lm] = xa.z; As[lk + 3][lm] = xa.w;
    size_t wo = (size_t)(k0 + wk) * DD + n0 + wn;
    *(float4*)&Bq[wk][wn] = *(const float4*)&Wq[wo];
    *(float4*)&Bk[wk][wn] = *(const float4*)&Wk[wo];
    *(float4*)&Bv[wk][wn] = *(const float4*)&Wv[wo];
    __syncthreads();
    #pragma unroll
    for (int k = 0; k < 16; k++) {
      float4 a4 = *(float4*)&As[k][tm];
      float4 q4 = *(float4*)&Bq[k][tn];
      float4 k4 = *(float4*)&Bk[k][tn];
      float4 v4 = *(float4*)&Bv[k][tn];
      float a[4]  = {a4.x, a4.y, a4.z, a4.w};
      float qb[4] = {q4.x, q4.y, q4.z, q4.w};
      float kb[4] = {k4.x, k4.y, k4.z, k4.w};
      float vb[4] = {v4.x, v4.y, v4.z, v4.w};
      #pragma unroll
      for (int i = 0; i < 4; i++)
        #pragma unroll
        for (int j = 0; j < 4; j++) {
          aq[i][j] = fmaf(a[i], qb[j], aq[i][j]);
          ak[i][j] = fmaf(a[i], kb[j], ak[i][j]);
          av[i][j] = fmaf(a[i], vb[j], av[i][j]);
        }
    }
  }
  #pragma unroll
  for (int i = 0; i < 4; i++) {
    size_t off = (size_t)(m0 + tm + i) * DD + n0 + tn;
    *(float4*)&Qo[off] = make_float4(aq[i][0], aq[i][1], aq[i][2], aq[i][3]);
    *(float4*)&Ko[off] = make_float4(ak[i][0], ak[i][1], ak[i][2], ak[i][3]);
    *(float4*)&Vo[off] = make_float4(av[i][0], av[i][1], av[i][2], av[i][3]);
  }
}

// ---------------- K3: flash attention (online softmax, fp32) ----------------
// QT=16 query rows per block, KT=16 keys per tile, 256 threads.
// Q read from global (broadcast, L1-resident 32KB tile); K staged in LDS;
// V streamed float4 from L2. Q lives in d_out; this block overwrites ONLY
// its own Q rows, after the final __syncthreads -> race-free.
__global__ __launch_bounds__(256) void k_attn(
    const float* __restrict__ Qg, const float* __restrict__ Kg,
    const float* __restrict__ Vg, float* __restrict__ Og)
{
  __shared__ float Ks[16][516];     // padded: 4-way-max bank aliasing on b128
  __shared__ float Ps[16][17];
  __shared__ float mS[16], lS[16], aS[16];
  int tid = threadIdx.x;
  int b  = blockIdx.y;
  int q0 = blockIdx.x * 16;
  int r  = tid >> 4;                // score row 0..15
  int kc = tid & 15;                // score col 0..15
  int rsel = tid >> 7;              // PV: rows rsel*8 .. rsel*8+7
  int d0 = (tid & 127) * 4;         // PV: 4 output cols
  const float* Qr = Qg + (size_t)(b * SS + q0 + r) * DD;
  float o[8][4];
  #pragma unroll
  for (int i = 0; i < 8; i++)
    #pragma unroll
    for (int j = 0; j < 4; j++) o[i][j] = 0.f;
  if (tid < 16) { mS[tid] = -1e30f; lS[tid] = 0.f; }
  const float scale = 0.044194173824159216f;   // 1/sqrt(512)
  for (int kt = 0; kt < SS / 16; kt++) {
    __syncthreads();
    const float* Kt = Kg + (size_t)(b * SS + kt * 16) * DD;
    #pragma unroll
    for (int u = 0; u < 8; u++) {
      int t = tid + u * 256;
      int kr = t >> 7, c4 = (t & 127) * 4;
      *(float4*)&Ks[kr][c4] = *(const float4*)&Kt[(size_t)kr * DD + c4];
    }
    __syncthreads();
    // scores: one (r,kc) per thread
    float s = 0.f;
    #pragma unroll 4
    for (int d4 = 0; d4 < DD; d4 += 4) {
      float4 q4 = *(const float4*)&Qr[d4];
      float4 k4 = *(const float4*)&Ks[kc][d4];
      s = fmaf(q4.x, k4.x, s); s = fmaf(q4.y, k4.y, s);
      s = fmaf(q4.z, k4.z, s); s = fmaf(q4.w, k4.w, s);
    }
    s *= scale;
    // online softmax update (16-lane groups own one row each)
    float mx = s;
    #pragma unroll
    for (int off = 8; off > 0; off >>= 1)
      mx = fmaxf(mx, __shfl_xor(mx, off, 16));
    float mold = mS[r];
    float mnew = fmaxf(mold, mx);
    float p = expf(s - mnew);
    float psum = p;
    #pragma unroll
    for (int off = 8; off > 0; off >>= 1)
      psum += __shfl_xor(psum, off, 16);
    if (kc == 0) {
      float al = expf(mold - mnew);
      aS[r] = al;
      lS[r] = lS[r] * al + psum;
      mS[r] = mnew;
    }
    Ps[r][kc] = p;
    __syncthreads();
    // PV accumulate: thread owns 8 rows x 4 cols
    const float* Vt = Vg + (size_t)(b * SS + kt * 16) * DD + d0;
    #pragma unroll
    for (int i = 0; i < 8; i++) {
      float al = aS[rsel * 8 + i];
      #pragma unroll
      for (int j = 0; j < 4; j++) o[i][j] *= al;
    }
    #pragma unroll 4
    for (int k = 0; k < 16; k++) {
      float4 v4 = *(const float4*)&Vt[(size_t)k * DD];
      #pragma unroll
      for (int i = 0; i < 8; i++) {
        float p_ = Ps[rsel * 8 + i][k];
        o[i][0] = fmaf(p_, v4.x, o[i][0]);
        o[i][1] = fmaf(p_, v4.y, o[i][1]);
        o[i][2] = fmaf(p_, v4.z, o[i][2]);
        o[i][3] = fmaf(p_, v4.w, o[i][3]);
      }
    }
  }
  __syncthreads();   // REQUIRED: all Q reads done before overwriting d_out
  float* Ob = Og + (size_t)(b * SS + q0 + rsel * 8) * DD + d0;
  #pragma unroll
  for (int i = 0; i < 8; i++) {
    float inv = 1.0f / lS[rsel * 8 + i];
    float4 w;
    w.x = o[i][0] * inv; w.y = o[i][1] * inv;
    w.z = o[i][2] * inv; w.w = o[i][3] * inv;
    *(float4*)&Ob[(size_t)i * DD] = w;
  }
}

extern "C" void kernel_launch(void* const* d_in, const int* in_sizes, int n_in,
                              void* d_out, int out_size, void* d_ws, size_t ws_size,
                              hipStream_t stream) {
  // setup_inputs order: input, word_emb, pos_emb, gamma, beta, Wk, Wq, Wv
  const int*   inp   = (const int*)d_in[0];
  const float* wemb  = (const float*)d_in[1];
  const float* pemb  = (const float*)d_in[2];
  const float* gamma = (const float*)d_in[3];
  const float* beta  = (const float*)d_in[4];
  const float* Wk    = (const float*)d_in[5];
  const float* Wq    = (const float*)d_in[6];
  const float* Wv    = (const float*)d_in[7];

  // workspace layout: X (64MB) | K (64MB) | V (64MB)  -> needs 192MB ws
  float* X  = (float*)d_ws;
  float* Kp = X  + (size_t)BSROWS * DD;
  float* Vp = Kp + (size_t)BSROWS * DD;
  float* Qp = (float*)d_out;     // Q parked in d_out, consumed in-place by k_attn

  k_embed_ln<<<BSROWS, 256, 0, stream>>>(inp, wemb, pemb, gamma, beta, X);
  k_qkv<<<dim3(DD / 64, BSROWS / 64), 256, 0, stream>>>(X, Wq, Wk, Wv, Qp, Kp, Vp);
  k_attn<<<dim3(SS / 16, BB), 256, 0, stream>>>(Qp, Kp, Vp, (float*)d_out);
}

// Round 2
// 2076.151 us; speedup vs baseline: 1.5621x; 1.5621x over previous
//
#include <hip/hip_runtime.h>
#include <math.h>

#define BB 32
#define SS 1024
#define DD 512
#define BSROWS (BB*SS)   // 32768 rows

#define QT 32
#define KT 64
#define DK 128
#define NTILE (SS/KT)    // 16
#define NCH (DD/DK)      // 4

// ---------------- K1: embedding gather + layernorm ----------------
__global__ __launch_bounds__(256) void k_embed_ln(
    const int* __restrict__ inp, const float* __restrict__ wemb,
    const float* __restrict__ pemb, const float* __restrict__ gamma,
    const float* __restrict__ beta, float* __restrict__ X)
{
  int row = blockIdx.x;
  int s   = row & (SS - 1);
  int tid = threadIdx.x;
  int tok = inp[row];
  float2 w = ((const float2*)(wemb + (size_t)tok * DD))[tid];
  float2 p = ((const float2*)(pemb + (size_t)s   * DD))[tid];
  float ex = w.x + p.x, ey = w.y + p.y;
  float sum = ex + ey;
  float ssq = ex*ex + ey*ey;
  #pragma unroll
  for (int off = 32; off > 0; off >>= 1) {
    sum += __shfl_down(sum, off, 64);
    ssq += __shfl_down(ssq, off, 64);
  }
  __shared__ float red[10];
  int wv = tid >> 6, ln = tid & 63;
  if (ln == 0) { red[wv] = sum; red[4 + wv] = ssq; }
  __syncthreads();
  if (tid == 0) {
    float s4 = red[0] + red[1] + red[2] + red[3];
    float q4 = red[4] + red[5] + red[6] + red[7];
    float mean = s4 * (1.0f / DD);
    float var  = q4 * (1.0f / DD) - mean * mean;
    red[8] = mean;
    red[9] = rsqrtf(var + 1e-5f);
  }
  __syncthreads();
  float mean = red[8], rstd = red[9];
  float2 g  = ((const float2*)gamma)[tid];
  float2 bt = ((const float2*)beta)[tid];
  float2 o;
  o.x = (ex - mean) * rstd * g.x + bt.x;
  o.y = (ey - mean) * rstd * g.y + bt.y;
  ((float2*)(X + (size_t)row * DD))[tid] = o;
}

// ---------------- K2: fused QKV projection GEMM (fp32) ----------------
__global__ __launch_bounds__(256) void k_qkv(
    const float* __restrict__ X, const float* __restrict__ Wq,
    const float* __restrict__ Wk, const float* __restrict__ Wv,
    float* __restrict__ Qo, float* __restrict__ Ko, float* __restrict__ Vo)
{
  __shared__ float As[16][68];
  __shared__ float Bq[16][64], Bk[16][64], Bv[16][64];
  int tid = threadIdx.x;
  int n0 = blockIdx.x * 64;
  int m0 = blockIdx.y * 64;
  int lm = tid >> 2, lk = (tid & 3) * 4;
  int wk = tid >> 4, wn = (tid & 15) * 4;
  int tm = (tid >> 4) * 4, tn = (tid & 15) * 4;
  float aq[4][4] = {{0}}, ak[4][4] = {{0}}, av[4][4] = {{0}};
  for (int k0 = 0; k0 < DD; k0 += 16) {
    __syncthreads();
    float4 xa = *(const float4*)&X[(size_t)(m0 + lm) * DD + k0 + lk];
    As[lk + 0][lm] = xa.x; As[lk + 1][lm] = xa.y;
    As[lk + 2][lm] = xa.z; As[lk + 3][lm] = xa.w;
    size_t wo = (size_t)(k0 + wk) * DD + n0 + wn;
    *(float4*)&Bq[wk][wn] = *(const float4*)&Wq[wo];
    *(float4*)&Bk[wk][wn] = *(const float4*)&Wk[wo];
    *(float4*)&Bv[wk][wn] = *(const float4*)&Wv[wo];
    __syncthreads();
    #pragma unroll
    for (int k = 0; k < 16; k++) {
      float4 a4 = *(float4*)&As[k][tm];
      float4 q4 = *(float4*)&Bq[k][tn];
      float4 k4 = *(float4*)&Bk[k][tn];
      float4 v4 = *(float4*)&Bv[k][tn];
      float a[4]  = {a4.x, a4.y, a4.z, a4.w};
      float qb[4] = {q4.x, q4.y, q4.z, q4.w};
      float kb[4] = {k4.x, k4.y, k4.z, k4.w};
      float vb[4] = {v4.x, v4.y, v4.z, v4.w};
      #pragma unroll
      for (int i = 0; i < 4; i++)
        #pragma unroll
        for (int j = 0; j < 4; j++) {
          aq[i][j] = fmaf(a[i], qb[j], aq[i][j]);
          ak[i][j] = fmaf(a[i], kb[j], ak[i][j]);
          av[i][j] = fmaf(a[i], vb[j], av[i][j]);
        }
    }
  }
  #pragma unroll
  for (int i = 0; i < 4; i++) {
    size_t off = (size_t)(m0 + tm + i) * DD + n0 + tn;
    *(float4*)&Qo[off] = make_float4(aq[i][0], aq[i][1], aq[i][2], aq[i][3]);
    *(float4*)&Ko[off] = make_float4(ak[i][0], ak[i][1], ak[i][2], ak[i][3]);
    *(float4*)&Vo[off] = make_float4(av[i][0], av[i][1], av[i][2], av[i][3]);
  }
}

// ---------------- K3: register-blocked flash attention (fp32) ----------------
// QT=32 q-rows/block, KT=64 keys/tile, 256 threads as 16x16 (i=row-group, j).
// QK: thread owns rows {2i,2i+1} x cols {j,j+16,j+32,j+48}; Q,K staged in LDS
// in DK=128 d-chunks; all Q reads are 16-lane broadcasts.
// Softmax state (m,l,alpha) kept redundantly in registers per row-group.
// PV: same thread owns rows {2i,2i+1} x cols {4j..4j+3, 64+4j..} per d-chunk;
// P round-trips LDS once; V streams through the K LDS buffer.
__global__ __launch_bounds__(256, 2) void k_attn2(
    const float* __restrict__ Qg, const float* __restrict__ Kg,
    const float* __restrict__ Vg, float* __restrict__ Og)
{
  __shared__ float Qs[QT][DK + 4];
  __shared__ float KVs[KT][DK + 4];
  __shared__ float Ps[QT][KT + 4];
  int tid = threadIdx.x;
  int b  = blockIdx.y;
  int q0 = blockIdx.x * QT;
  int i = tid >> 4, j = tid & 15;
  int r0 = 2 * i, r1 = 2 * i + 1;
  int c4 = tid & 31;          // staging col (float4 index)
  int rq = tid >> 5;          // staging row base

  float o[2][NCH][2][4];
  #pragma unroll
  for (int u = 0; u < 2; u++)
    #pragma unroll
    for (int c = 0; c < NCH; c++)
      #pragma unroll
      for (int h = 0; h < 2; h++)
        #pragma unroll
        for (int x = 0; x < 4; x++) o[u][c][h][x] = 0.f;
  float m_run[2] = {-1e30f, -1e30f};
  float l_run[2] = {0.f, 0.f};
  const float scale = 0.044194173824159216f;   // 1/sqrt(512)

  const size_t qbase  = (size_t)(b * SS + q0) * DD;
  const size_t kvbase = (size_t)(b * SS) * DD;

  for (int kt = 0; kt < NTILE; kt++) {
    float s[2][4] = {{0.f,0.f,0.f,0.f},{0.f,0.f,0.f,0.f}};
    // ---- QK phase over d-chunks ----
    for (int c = 0; c < NCH; c++) {
      __syncthreads();   // protect prior reads of Qs/KVs
      #pragma unroll
      for (int rr = 0; rr < QT / 8; rr++)
        *(float4*)&Qs[rq + 8 * rr][4 * c4] =
          *(const float4*)&Qg[qbase + (size_t)(rq + 8 * rr) * DD + c * DK + 4 * c4];
      #pragma unroll
      for (int rr = 0; rr < KT / 8; rr++)
        *(float4*)&KVs[rq + 8 * rr][4 * c4] =
          *(const float4*)&Kg[kvbase + (size_t)(kt * KT + rq + 8 * rr) * DD + c * DK + 4 * c4];
      __syncthreads();
      #pragma unroll 4
      for (int d4 = 0; d4 < DK / 4; d4++) {
        float4 qa4 = *(const float4*)&Qs[r0][4 * d4];
        float4 qb4 = *(const float4*)&Qs[r1][4 * d4];
        float4 k0v = *(const float4*)&KVs[j     ][4 * d4];
        float4 k1v = *(const float4*)&KVs[j + 16][4 * d4];
        float4 k2v = *(const float4*)&KVs[j + 32][4 * d4];
        float4 k3v = *(const float4*)&KVs[j + 48][4 * d4];
        float qa[2][4] = {{qa4.x, qa4.y, qa4.z, qa4.w}, {qb4.x, qb4.y, qb4.z, qb4.w}};
        float kb[4][4] = {{k0v.x, k0v.y, k0v.z, k0v.w}, {k1v.x, k1v.y, k1v.z, k1v.w},
                          {k2v.x, k2v.y, k2v.z, k2v.w}, {k3v.x, k3v.y, k3v.z, k3v.w}};
        #pragma unroll
        for (int u = 0; u < 2; u++)
          #pragma unroll
          for (int w = 0; w < 4; w++)
            #pragma unroll
            for (int d = 0; d < 4; d++)
              s[u][w] = fmaf(qa[u][d], kb[w][d], s[u][w]);
      }
    }
    // ---- online softmax (all state in registers; 16-lane shuffles) ----
    float al[2];
    #pragma unroll
    for (int u = 0; u < 2; u++) {
      #pragma unroll
      for (int w = 0; w < 4; w++) s[u][w] *= scale;
      float mx = fmaxf(fmaxf(s[u][0], s[u][1]), fmaxf(s[u][2], s[u][3]));
      #pragma unroll
      for (int off = 8; off > 0; off >>= 1)
        mx = fmaxf(mx, __shfl_xor(mx, off, 16));
      float mnew = fmaxf(m_run[u], mx);
      al[u] = __expf(m_run[u] - mnew);
      float ps = 0.f;
      #pragma unroll
      for (int w = 0; w < 4; w++) { s[u][w] = __expf(s[u][w] - mnew); ps += s[u][w]; }
      #pragma unroll
      for (int off = 8; off > 0; off >>= 1)
        ps += __shfl_xor(ps, off, 16);
      l_run[u] = l_run[u] * al[u] + ps;
      m_run[u] = mnew;
    }
    __syncthreads();   // QK reads of KVs done; prev-tile Ps reads long done
    #pragma unroll
    for (int u = 0; u < 2; u++)
      #pragma unroll
      for (int w = 0; w < 4; w++)
        Ps[2 * i + u][j + 16 * w] = s[u][w];
    // rescale O accumulator
    #pragma unroll
    for (int u = 0; u < 2; u++)
      #pragma unroll
      for (int c = 0; c < NCH; c++)
        #pragma unroll
        for (int h = 0; h < 2; h++)
          #pragma unroll
          for (int x = 0; x < 4; x++) o[u][c][h][x] *= al[u];
    // ---- PV phase over d-chunks (V through KVs buffer) ----
    for (int c = 0; c < NCH; c++) {
      __syncthreads();   // protect prior reads of KVs (and publish Ps on c==0)
      #pragma unroll
      for (int rr = 0; rr < KT / 8; rr++)
        *(float4*)&KVs[rq + 8 * rr][4 * c4] =
          *(const float4*)&Vg[kvbase + (size_t)(kt * KT + rq + 8 * rr) * DD + c * DK + 4 * c4];
      __syncthreads();
      #pragma unroll 4
      for (int k = 0; k < KT; k++) {
        float p0 = Ps[r0][k];
        float p1 = Ps[r1][k];
        float4 va = *(const float4*)&KVs[k][4 * j];
        float4 vb = *(const float4*)&KVs[k][64 + 4 * j];
        o[0][c][0][0] = fmaf(p0, va.x, o[0][c][0][0]);
        o[0][c][0][1] = fmaf(p0, va.y, o[0][c][0][1]);
        o[0][c][0][2] = fmaf(p0, va.z, o[0][c][0][2]);
        o[0][c][0][3] = fmaf(p0, va.w, o[0][c][0][3]);
        o[0][c][1][0] = fmaf(p0, vb.x, o[0][c][1][0]);
        o[0][c][1][1] = fmaf(p0, vb.y, o[0][c][1][1]);
        o[0][c][1][2] = fmaf(p0, vb.z, o[0][c][1][2]);
        o[0][c][1][3] = fmaf(p0, vb.w, o[0][c][1][3]);
        o[1][c][0][0] = fmaf(p1, va.x, o[1][c][0][0]);
        o[1][c][0][1] = fmaf(p1, va.y, o[1][c][0][1]);
        o[1][c][0][2] = fmaf(p1, va.z, o[1][c][0][2]);
        o[1][c][0][3] = fmaf(p1, va.w, o[1][c][0][3]);
        o[1][c][1][0] = fmaf(p1, vb.x, o[1][c][1][0]);
        o[1][c][1][1] = fmaf(p1, vb.y, o[1][c][1][1]);
        o[1][c][1][2] = fmaf(p1, vb.z, o[1][c][1][2]);
        o[1][c][1][3] = fmaf(p1, vb.w, o[1][c][1][3]);
      }
    }
  }
  // ---- epilogue: normalize and store (only this block's own rows) ----
  float inv[2] = {1.f / l_run[0], 1.f / l_run[1]};
  #pragma unroll
  for (int u = 0; u < 2; u++)
    #pragma unroll
    for (int c = 0; c < NCH; c++)
      #pragma unroll
      for (int h = 0; h < 2; h++) {
        float4 wv;
        wv.x = o[u][c][h][0] * inv[u];
        wv.y = o[u][c][h][1] * inv[u];
        wv.z = o[u][c][h][2] * inv[u];
        wv.w = o[u][c][h][3] * inv[u];
        *(float4*)&Og[qbase + (size_t)(2 * i + u) * DD + c * DK + h * 64 + 4 * j] = wv;
      }
}

extern "C" void kernel_launch(void* const* d_in, const int* in_sizes, int n_in,
                              void* d_out, int out_size, void* d_ws, size_t ws_size,
                              hipStream_t stream) {
  const int*   inp   = (const int*)d_in[0];
  const float* wemb  = (const float*)d_in[1];
  const float* pemb  = (const float*)d_in[2];
  const float* gamma = (const float*)d_in[3];
  const float* beta  = (const float*)d_in[4];
  const float* Wk    = (const float*)d_in[5];
  const float* Wq    = (const float*)d_in[6];
  const float* Wv    = (const float*)d_in[7];

  float* X  = (float*)d_ws;
  float* Kp = X  + (size_t)BSROWS * DD;
  float* Vp = Kp + (size_t)BSROWS * DD;
  float* Qp = (float*)d_out;   // Q parked in d_out; k_attn2 reads/writes only its own rows

  k_embed_ln<<<BSROWS, 256, 0, stream>>>(inp, wemb, pemb, gamma, beta, X);
  k_qkv<<<dim3(DD / 64, BSROWS / 64), 256, 0, stream>>>(X, Wq, Wk, Wv, Qp, Kp, Vp);
  k_attn2<<<dim3(SS / QT, BB), 256, 0, stream>>>(Qp, Kp, Vp, (float*)d_out);
}

// Round 3
// 548.065 us; speedup vs baseline: 5.9176x; 3.7881x over previous
//
#include <hip/hip_runtime.h>
#include <math.h>

typedef _Float16 f16;
typedef _Float16 half8 __attribute__((ext_vector_type(8)));
typedef _Float16 h2 __attribute__((ext_vector_type(2)));
typedef _Float16 h4 __attribute__((ext_vector_type(4)));
typedef float f32x4 __attribute__((ext_vector_type(4)));
typedef __attribute__((address_space(1))) const unsigned int gu32;
typedef __attribute__((address_space(3))) unsigned int lu32;

#define BB 32
#define SS 1024
#define DD 512
#define NR (BB*SS)   // 32768

// ---------- shared helpers for the m97-style GEMM pattern ----------
// LDS tile: [128 rows][64 k] fp16, 128 B/row, 16B chunks XOR-swizzled by (row&7).
// Staged with global_load_lds width=16: lds slot (lane-linear) at (row, cp) holds
// global chunk c = cp ^ (row&7)  ->  reads at chunk kc use phys kc ^ (row&7).
__device__ __forceinline__ void stage_tile(const char* g, int ldb, char* lds,
                                           int wv, int ln) {
  #pragma unroll
  for (int r = 0; r < 4; r++) {
    int slot = r * 256 + wv * 64 + ln;
    int row = slot >> 3, cp = slot & 7;
    int c = cp ^ (row & 7);
    const char* gp = g + (size_t)row * ldb + (c << 4);
    char* lp = lds + ((slot - ln) << 4);           // wave-uniform base
    __builtin_amdgcn_global_load_lds((gu32*)gp, (lu32*)lp, 16, 0, 0);
  }
}

__device__ __forceinline__ half8 frag_ld(const char* lds, int row, int kc) {
  return *(const half8*)(lds + row * 128 + ((kc ^ (row & 7)) << 4));
}

__device__ __forceinline__ f32x4 MF(half8 a, half8 b, f32x4 c) {
  return __builtin_amdgcn_mfma_f32_16x16x32_f16(a, b, c, 0, 0, 0);
}

// P (fp16 [32768][1024]) overlays dead Q rows per 8-batch chunk:
// chunk c's P (16 MB) -> Qhi rows [c*8192..) (8 MB) + Qlo rows same (8 MB).
// Returns byte offset from (ws + 64 MiB).
__device__ __forceinline__ size_t p_row_off(int grow) {
  int c = grow >> 13;
  int r = grow & 8191;
  return ((size_t)c << 23) + ((r >> 12) ? ((size_t)32 << 20) : 0)
         + (size_t)(r & 4095) * 2048;
}

// ---------------- K1: embedding gather + layernorm -> split fp16 X ----------------
__global__ __launch_bounds__(256) void k_embed_ln(
    const int* __restrict__ inp, const float* __restrict__ wemb,
    const float* __restrict__ pemb, const float* __restrict__ gamma,
    const float* __restrict__ beta, f16* __restrict__ Xhi, f16* __restrict__ Xlo)
{
  int row = blockIdx.x;
  int s   = row & (SS - 1);
  int tid = threadIdx.x;
  int tok = inp[row];
  float2 w = ((const float2*)(wemb + (size_t)tok * DD))[tid];
  float2 p = ((const float2*)(pemb + (size_t)s   * DD))[tid];
  float ex = w.x + p.x, ey = w.y + p.y;
  float sum = ex + ey, ssq = ex*ex + ey*ey;
  #pragma unroll
  for (int off = 32; off > 0; off >>= 1) {
    sum += __shfl_down(sum, off, 64);
    ssq += __shfl_down(ssq, off, 64);
  }
  __shared__ float red[10];
  int wv = tid >> 6, ln = tid & 63;
  if (ln == 0) { red[wv] = sum; red[4 + wv] = ssq; }
  __syncthreads();
  if (tid == 0) {
    float s4 = red[0] + red[1] + red[2] + red[3];
    float q4 = red[4] + red[5] + red[6] + red[7];
    float mean = s4 * (1.0f / DD);
    float var  = q4 * (1.0f / DD) - mean * mean;
    red[8] = mean; red[9] = rsqrtf(var + 1e-5f);
  }
  __syncthreads();
  float mean = red[8], rstd = red[9];
  float2 g  = ((const float2*)gamma)[tid];
  float2 bt = ((const float2*)beta)[tid];
  float ox = (ex - mean) * rstd * g.x + bt.x;
  float oy = (ey - mean) * rstd * g.y + bt.y;
  f16 hx = (f16)ox, hy = (f16)oy;
  f16 lx = (f16)(ox - (float)hx), ly = (f16)(oy - (float)hy);
  ((h2*)(Xhi + (size_t)row * DD))[tid] = (h2){hx, hy};
  ((h2*)(Xlo + (size_t)row * DD))[tid] = (h2){lx, ly};
}

// ---------------- K2: weight prep: transpose + split ----------------
// Wt[d][c]: Wq,Wk split hi/lo; Wv plain fp16 (Wvt is A-operand of the Vt GEMM).
__global__ __launch_bounds__(256) void k_prep_w(
    const float* __restrict__ Wq, const float* __restrict__ Wk,
    const float* __restrict__ Wv, f16* __restrict__ Wqth, f16* __restrict__ Wqtl,
    f16* __restrict__ Wkth, f16* __restrict__ Wktl, f16* __restrict__ Wvt)
{
  int d = blockIdx.x;
  for (int c = threadIdx.x; c < DD; c += 256) {
    float q = Wq[(size_t)c * DD + d];
    float k = Wk[(size_t)c * DD + d];
    float v = Wv[(size_t)c * DD + d];
    f16 qh = (f16)q, kh = (f16)k;
    size_t o = (size_t)d * DD + c;
    Wqth[o] = qh; Wqtl[o] = (f16)(q - (float)qh);
    Wkth[o] = kh; Wktl[o] = (f16)(k - (float)kh);
    Wvt[o]  = (f16)v;
  }
}

// ---------------- K3: Q/K projection, split x split (3-term MFMA) ----------------
// C[s][d] = X[s][:] * W[:][d];  A = X split, B = Wt split. Epilogue re-splits to fp16.
__global__ __launch_bounds__(256, 2) void k_proj(
    const f16* __restrict__ Xhi, const f16* __restrict__ Xlo,
    const f16* __restrict__ Bth, const f16* __restrict__ Btl,
    f16* __restrict__ Ohi, f16* __restrict__ Olo)
{
  __shared__ __align__(16) char Ah[16384], Al[16384], Bh[16384], Bl[16384];
  int tid = threadIdx.x, wv = tid >> 6, ln = tid & 63;
  int mw = wv & 1, nw = wv >> 1;
  int n0 = blockIdx.x * 128;   // d
  int m0 = blockIdx.y * 128;   // s
  f32x4 acc[4][4];
  #pragma unroll
  for (int i = 0; i < 4; i++)
    #pragma unroll
    for (int j = 0; j < 4; j++) acc[i][j] = (f32x4)(0.0f);
  for (int k0 = 0; k0 < DD; k0 += 64) {
    __syncthreads();
    stage_tile((const char*)(Xhi + (size_t)m0 * DD + k0), 1024, Ah, wv, ln);
    stage_tile((const char*)(Xlo + (size_t)m0 * DD + k0), 1024, Al, wv, ln);
    stage_tile((const char*)(Bth + (size_t)n0 * DD + k0), 1024, Bh, wv, ln);
    stage_tile((const char*)(Btl + (size_t)n0 * DD + k0), 1024, Bl, wv, ln);
    __syncthreads();
    int quad = ln >> 4, l15 = ln & 15;
    #pragma unroll
    for (int ks = 0; ks < 2; ks++) {
      int kc = ks * 4 + quad;
      half8 ah[4], al[4], bh[4], bl[4];
      #pragma unroll
      for (int t = 0; t < 4; t++) {
        int mr = mw * 64 + t * 16 + l15;
        int nr = nw * 64 + t * 16 + l15;
        ah[t] = frag_ld(Ah, mr, kc); al[t] = frag_ld(Al, mr, kc);
        bh[t] = frag_ld(Bh, nr, kc); bl[t] = frag_ld(Bl, nr, kc);
      }
      #pragma unroll
      for (int i = 0; i < 4; i++)
        #pragma unroll
        for (int j = 0; j < 4; j++) {
          acc[i][j] = MF(ah[i], bh[j], acc[i][j]);
          acc[i][j] = MF(ah[i], bl[j], acc[i][j]);
          acc[i][j] = MF(al[i], bh[j], acc[i][j]);
        }
    }
  }
  int quad = ln >> 4, l15 = ln & 15;
  #pragma unroll
  for (int i = 0; i < 4; i++)
    #pragma unroll
    for (int j = 0; j < 4; j++)
      #pragma unroll
      for (int rg = 0; rg < 4; rg++) {
        int gm = m0 + mw * 64 + i * 16 + quad * 4 + rg;
        int gn = n0 + nw * 64 + j * 16 + l15;
        float v = acc[i][j][rg];
        f16 h = (f16)v;
        size_t o = (size_t)gm * DD + gn;
        Ohi[o] = h; Olo[o] = (f16)(v - (float)h);
      }
}

// ---------------- K4: Vt GEMM (plain fp16): Vt[d][s] = sum_c Wvt[d][c] * X[s][c] --------
__global__ __launch_bounds__(256, 2) void k_vt(
    const f16* __restrict__ Wvt, const f16* __restrict__ Xhi, f16* __restrict__ Vt)
{
  __shared__ __align__(16) char Ah[16384], Bh[16384];
  int tid = threadIdx.x, wv = tid >> 6, ln = tid & 63;
  int mw = wv & 1, nw = wv >> 1;
  int n0 = blockIdx.x * 128;   // s
  int m0 = blockIdx.y * 128;   // d
  f32x4 acc[4][4];
  #pragma unroll
  for (int i = 0; i < 4; i++)
    #pragma unroll
    for (int j = 0; j < 4; j++) acc[i][j] = (f32x4)(0.0f);
  for (int k0 = 0; k0 < DD; k0 += 64) {
    __syncthreads();
    stage_tile((const char*)(Wvt + (size_t)m0 * DD + k0), 1024, Ah, wv, ln);
    stage_tile((const char*)(Xhi + (size_t)n0 * DD + k0), 1024, Bh, wv, ln);
    __syncthreads();
    int quad = ln >> 4, l15 = ln & 15;
    #pragma unroll
    for (int ks = 0; ks < 2; ks++) {
      int kc = ks * 4 + quad;
      half8 a[4], b[4];
      #pragma unroll
      for (int t = 0; t < 4; t++) {
        a[t] = frag_ld(Ah, mw * 64 + t * 16 + l15, kc);
        b[t] = frag_ld(Bh, nw * 64 + t * 16 + l15, kc);
      }
      #pragma unroll
      for (int i = 0; i < 4; i++)
        #pragma unroll
        for (int j = 0; j < 4; j++) acc[i][j] = MF(a[i], b[j], acc[i][j]);
    }
  }
  int quad = ln >> 4, l15 = ln & 15;
  #pragma unroll
  for (int i = 0; i < 4; i++)
    #pragma unroll
    for (int j = 0; j < 4; j++)
      #pragma unroll
      for (int rg = 0; rg < 4; rg++) {
        int gm = m0 + mw * 64 + i * 16 + quad * 4 + rg;   // d
        int gn = n0 + nw * 64 + j * 16 + l15;             // s
        Vt[(size_t)gm * NR + gn] = (f16)acc[i][j][rg];
      }
}

// ---------------- K5: S = Q K^T / sqrt(D), split x split, per 8-batch chunk ----------
__global__ __launch_bounds__(256, 2) void k_qk(
    const f16* __restrict__ Qhi, const f16* __restrict__ Qlo,
    const f16* __restrict__ Khi, const f16* __restrict__ Klo,
    float* __restrict__ S, int chunk)
{
  __shared__ __align__(16) char Ah[16384], Al[16384], Bh[16384], Bl[16384];
  int tid = threadIdx.x, wv = tid >> 6, ln = tid & 63;
  int mw = wv & 1, nw = wv >> 1;
  int n0 = blockIdx.x * 128;          // key
  int m0 = blockIdx.y * 128;          // query
  int z  = blockIdx.z;                // batch within chunk
  size_t brow = ((size_t)chunk * 8 + z) * SS;
  f32x4 acc[4][4];
  #pragma unroll
  for (int i = 0; i < 4; i++)
    #pragma unroll
    for (int j = 0; j < 4; j++) acc[i][j] = (f32x4)(0.0f);
  for (int k0 = 0; k0 < DD; k0 += 64) {
    __syncthreads();
    stage_tile((const char*)(Qhi + (brow + m0) * DD + k0), 1024, Ah, wv, ln);
    stage_tile((const char*)(Qlo + (brow + m0) * DD + k0), 1024, Al, wv, ln);
    stage_tile((const char*)(Khi + (brow + n0) * DD + k0), 1024, Bh, wv, ln);
    stage_tile((const char*)(Klo + (brow + n0) * DD + k0), 1024, Bl, wv, ln);
    __syncthreads();
    int quad = ln >> 4, l15 = ln & 15;
    #pragma unroll
    for (int ks = 0; ks < 2; ks++) {
      int kc = ks * 4 + quad;
      half8 ah[4], al[4], bh[4], bl[4];
      #pragma unroll
      for (int t = 0; t < 4; t++) {
        ah[t] = frag_ld(Ah, mw * 64 + t * 16 + l15, kc);
        al[t] = frag_ld(Al, mw * 64 + t * 16 + l15, kc);
        bh[t] = frag_ld(Bh, nw * 64 + t * 16 + l15, kc);
        bl[t] = frag_ld(Bl, nw * 64 + t * 16 + l15, kc);
      }
      #pragma unroll
      for (int i = 0; i < 4; i++)
        #pragma unroll
        for (int j = 0; j < 4; j++) {
          acc[i][j] = MF(ah[i], bh[j], acc[i][j]);
          acc[i][j] = MF(ah[i], bl[j], acc[i][j]);
          acc[i][j] = MF(al[i], bh[j], acc[i][j]);
        }
    }
  }
  const float scale = 0.044194173824159216f;   // 1/sqrt(512)
  int quad = ln >> 4, l15 = ln & 15;
  #pragma unroll
  for (int i = 0; i < 4; i++)
    #pragma unroll
    for (int j = 0; j < 4; j++)
      #pragma unroll
      for (int rg = 0; rg < 4; rg++) {
        int gm = m0 + mw * 64 + i * 16 + quad * 4 + rg;
        int gn = n0 + nw * 64 + j * 16 + l15;
        S[((size_t)z * SS + gm) * SS + gn] = acc[i][j][rg] * scale;
      }
}

// ---------------- K6: row softmax S(fp32) -> P(fp16, overlaying dead Q rows) -------
__global__ __launch_bounds__(256) void k_softmax(
    const float* __restrict__ S, char* __restrict__ Pb, int chunk)
{
  int rc = blockIdx.x;                 // row within chunk, 0..8191
  int tid = threadIdx.x;
  const float* row = S + (size_t)rc * SS;
  float4 v = ((const float4*)row)[tid];
  float mx = fmaxf(fmaxf(v.x, v.y), fmaxf(v.z, v.w));
  #pragma unroll
  for (int off = 32; off > 0; off >>= 1) mx = fmaxf(mx, __shfl_xor(mx, off, 64));
  __shared__ float red[10];
  int wv = tid >> 6;
  if ((tid & 63) == 0) red[wv] = mx;
  __syncthreads();
  if (tid == 0) red[8] = fmaxf(fmaxf(red[0], red[1]), fmaxf(red[2], red[3]));
  __syncthreads();
  mx = red[8];
  float e0 = __expf(v.x - mx), e1 = __expf(v.y - mx);
  float e2 = __expf(v.z - mx), e3 = __expf(v.w - mx);
  float sm = e0 + e1 + e2 + e3;
  #pragma unroll
  for (int off = 32; off > 0; off >>= 1) sm += __shfl_xor(sm, off, 64);
  if ((tid & 63) == 0) red[4 + wv] = sm;
  __syncthreads();
  if (tid == 0) red[9] = red[4] + red[5] + red[6] + red[7];
  __syncthreads();
  float inv = 1.0f / red[9];
  int grow = chunk * 8192 + rc;
  char* pb = Pb + p_row_off(grow);
  ((h4*)pb)[tid] = (h4){(f16)(e0 * inv), (f16)(e1 * inv), (f16)(e2 * inv), (f16)(e3 * inv)};
}

// ---------------- K7: O = P V  (plain fp16 MFMA), O fp32 to d_out ----------------
__global__ __launch_bounds__(256, 2) void k_pv(
    const char* __restrict__ Pb, const f16* __restrict__ Vt, float* __restrict__ O)
{
  __shared__ __align__(16) char Ah[16384], Bh[16384];
  int tid = threadIdx.x, wv = tid >> 6, ln = tid & 63;
  int mw = wv & 1, nw = wv >> 1;
  int n0 = blockIdx.x * 128;          // d_out
  int m0 = blockIdx.y * 128;          // query (within batch)
  int b  = blockIdx.z;
  int grow = b * SS + m0;
  const char* Pt = Pb + p_row_off(grow);
  f32x4 acc[4][4];
  #pragma unroll
  for (int i = 0; i < 4; i++)
    #pragma unroll
    for (int j = 0; j < 4; j++) acc[i][j] = (f32x4)(0.0f);
  for (int k0 = 0; k0 < SS; k0 += 64) {
    __syncthreads();
    stage_tile(Pt + k0 * 2, 2048, Ah, wv, ln);
    stage_tile((const char*)(Vt + (size_t)n0 * NR + (size_t)b * SS + k0), NR * 2, Bh, wv, ln);
    __syncthreads();
    int quad = ln >> 4, l15 = ln & 15;
    #pragma unroll
    for (int ks = 0; ks < 2; ks++) {
      int kc = ks * 4 + quad;
      half8 a[4], bf[4];
      #pragma unroll
      for (int t = 0; t < 4; t++) {
        a[t]  = frag_ld(Ah, mw * 64 + t * 16 + l15, kc);
        bf[t] = frag_ld(Bh, nw * 64 + t * 16 + l15, kc);
      }
      #pragma unroll
      for (int i = 0; i < 4; i++)
        #pragma unroll
        for (int j = 0; j < 4; j++) acc[i][j] = MF(a[i], bf[j], acc[i][j]);
    }
  }
  int quad = ln >> 4, l15 = ln & 15;
  #pragma unroll
  for (int i = 0; i < 4; i++)
    #pragma unroll
    for (int j = 0; j < 4; j++)
      #pragma unroll
      for (int rg = 0; rg < 4; rg++) {
        int gm = m0 + mw * 64 + i * 16 + quad * 4 + rg;
        int gn = n0 + nw * 64 + j * 16 + l15;
        O[((size_t)b * SS + gm) * DD + gn] = acc[i][j][rg];
      }
}

extern "C" void kernel_launch(void* const* d_in, const int* in_sizes, int n_in,
                              void* d_out, int out_size, void* d_ws, size_t ws_size,
                              hipStream_t stream) {
  const int*   inp   = (const int*)d_in[0];
  const float* wemb  = (const float*)d_in[1];
  const float* pemb  = (const float*)d_in[2];
  const float* gamma = (const float*)d_in[3];
  const float* beta  = (const float*)d_in[4];
  const float* Wk    = (const float*)d_in[5];
  const float* Wq    = (const float*)d_in[6];
  const float* Wv    = (const float*)d_in[7];

  // ws (192 MiB): [Xhi 32M][Xlo 32M][Qhi 32M][Qlo 32M][Khi 32M][Klo 32M]
  // overlays: Sbuf(32M)->Xhi after k_vt; Vt(32M)->Xlo after k_proj; P(64M)->Q rows per chunk
  char* ws = (char*)d_ws;
  f16* Xhi = (f16*)ws;
  f16* Xlo = (f16*)(ws + ((size_t)32 << 20));
  f16* Qhi = (f16*)(ws + ((size_t)64 << 20));
  f16* Qlo = (f16*)(ws + ((size_t)96 << 20));
  f16* Khi = (f16*)(ws + ((size_t)128 << 20));
  f16* Klo = (f16*)(ws + ((size_t)160 << 20));
  float* Sbuf = (float*)ws;                       // over Xhi (dead after k_vt)
  f16* Vt  = (f16*)(ws + ((size_t)32 << 20));     // over Xlo (dead after k_proj)
  char* Pb = ws + ((size_t)64 << 20);             // over Q rows, chunk-interleaved

  // transposed/split weights parked at head of d_out (overwritten by O at the end)
  f16* Wqth = (f16*)d_out;
  f16* Wqtl = Wqth + (size_t)DD * DD;
  f16* Wkth = Wqtl + (size_t)DD * DD;
  f16* Wktl = Wkth + (size_t)DD * DD;
  f16* Wvt  = Wktl + (size_t)DD * DD;

  k_embed_ln<<<NR, 256, 0, stream>>>(inp, wemb, pemb, gamma, beta, Xhi, Xlo);
  k_prep_w<<<DD, 256, 0, stream>>>(Wq, Wk, Wv, Wqth, Wqtl, Wkth, Wktl, Wvt);
  k_proj<<<dim3(DD / 128, NR / 128), 256, 0, stream>>>(Xhi, Xlo, Wqth, Wqtl, Qhi, Qlo);
  k_proj<<<dim3(DD / 128, NR / 128), 256, 0, stream>>>(Xhi, Xlo, Wkth, Wktl, Khi, Klo);
  k_vt<<<dim3(NR / 128, DD / 128), 256, 0, stream>>>(Wvt, Xhi, Vt);
  for (int c = 0; c < 4; c++) {
    k_qk<<<dim3(SS / 128, SS / 128, 8), 256, 0, stream>>>(Qhi, Qlo, Khi, Klo, Sbuf, c);
    k_softmax<<<8192, 256, 0, stream>>>(Sbuf, Pb, c);
  }
  k_pv<<<dim3(DD / 128, SS / 128, BB), 256, 0, stream>>>(Pb, Vt, (float*)d_out);
}

// Round 4
// 535.827 us; speedup vs baseline: 6.0527x; 1.0228x over previous
//
#include <hip/hip_runtime.h>
#include <math.h>

typedef _Float16 f16;
typedef _Float16 half8 __attribute__((ext_vector_type(8)));
typedef _Float16 h2 __attribute__((ext_vector_type(2)));
typedef _Float16 h4 __attribute__((ext_vector_type(4)));
typedef float f32x4 __attribute__((ext_vector_type(4)));
typedef __attribute__((address_space(1))) const unsigned int gu32;
typedef __attribute__((address_space(3))) unsigned int lu32;

#define BB 32
#define SS 1024
#define DD 512
#define NR (BB*SS)   // 32768

// ---------- m97-style staging helpers ----------
// LDS tile: [rows][64 k] fp16, 128 B/row, 16B chunks XOR-swizzled by (row&7).
__device__ __forceinline__ void stage128(const char* g, int ldb, char* lds,
                                         int wv, int ln) {
  #pragma unroll
  for (int r = 0; r < 4; r++) {
    int slot = r * 256 + wv * 64 + ln;
    int row = slot >> 3, cp = slot & 7;
    int c = cp ^ (row & 7);
    const char* gp = g + (size_t)row * ldb + (c << 4);
    char* lp = lds + ((slot - ln) << 4);
    __builtin_amdgcn_global_load_lds((gu32*)gp, (lu32*)lp, 16, 0, 0);
  }
}

__device__ __forceinline__ void stage64(const char* g, int ldb, char* lds,
                                        int wv, int ln) {
  #pragma unroll
  for (int r = 0; r < 2; r++) {
    int slot = r * 256 + wv * 64 + ln;
    int row = slot >> 3, cp = slot & 7;
    int c = cp ^ (row & 7);
    const char* gp = g + (size_t)row * ldb + (c << 4);
    char* lp = lds + ((slot - ln) << 4);
    __builtin_amdgcn_global_load_lds((gu32*)gp, (lu32*)lp, 16, 0, 0);
  }
}

__device__ __forceinline__ half8 frag_ld(const char* lds, int row, int kc) {
  return *(const half8*)(lds + row * 128 + ((kc ^ (row & 7)) << 4));
}

__device__ __forceinline__ f32x4 MF(half8 a, half8 b, f32x4 c) {
  return __builtin_amdgcn_mfma_f32_16x16x32_f16(a, b, c, 0, 0, 0);
}

// P (fp16 [32768][1024]) overlays dead Q rows per 8-batch chunk.
__device__ __forceinline__ size_t p_row_off(int grow) {
  int c = grow >> 13;
  int r = grow & 8191;
  return ((size_t)c << 23) + ((r >> 12) ? ((size_t)32 << 20) : 0)
         + (size_t)(r & 4095) * 2048;
}

// ---------------- K1: embedding gather + layernorm -> split fp16 X ----------------
__global__ __launch_bounds__(256) void k_embed_ln(
    const int* __restrict__ inp, const float* __restrict__ wemb,
    const float* __restrict__ pemb, const float* __restrict__ gamma,
    const float* __restrict__ beta, f16* __restrict__ Xhi, f16* __restrict__ Xlo)
{
  int row = blockIdx.x;
  int s   = row & (SS - 1);
  int tid = threadIdx.x;
  int tok = inp[row];
  float2 w = ((const float2*)(wemb + (size_t)tok * DD))[tid];
  float2 p = ((const float2*)(pemb + (size_t)s   * DD))[tid];
  float ex = w.x + p.x, ey = w.y + p.y;
  float sum = ex + ey, ssq = ex*ex + ey*ey;
  #pragma unroll
  for (int off = 32; off > 0; off >>= 1) {
    sum += __shfl_down(sum, off, 64);
    ssq += __shfl_down(ssq, off, 64);
  }
  __shared__ float red[10];
  int wv = tid >> 6, ln = tid & 63;
  if (ln == 0) { red[wv] = sum; red[4 + wv] = ssq; }
  __syncthreads();
  if (tid == 0) {
    float s4 = red[0] + red[1] + red[2] + red[3];
    float q4 = red[4] + red[5] + red[6] + red[7];
    float mean = s4 * (1.0f / DD);
    float var  = q4 * (1.0f / DD) - mean * mean;
    red[8] = mean; red[9] = rsqrtf(var + 1e-5f);
  }
  __syncthreads();
  float mean = red[8], rstd = red[9];
  float2 g  = ((const float2*)gamma)[tid];
  float2 bt = ((const float2*)beta)[tid];
  float ox = (ex - mean) * rstd * g.x + bt.x;
  float oy = (ey - mean) * rstd * g.y + bt.y;
  f16 hx = (f16)ox, hy = (f16)oy;
  f16 lx = (f16)(ox - (float)hx), ly = (f16)(oy - (float)hy);
  ((h2*)(Xhi + (size_t)row * DD))[tid] = (h2){hx, hy};
  ((h2*)(Xlo + (size_t)row * DD))[tid] = (h2){lx, ly};
}

// ---------------- K2: weight prep: transpose + split ----------------
__global__ __launch_bounds__(256) void k_prep_w(
    const float* __restrict__ Wq, const float* __restrict__ Wk,
    const float* __restrict__ Wv, f16* __restrict__ Wqth, f16* __restrict__ Wqtl,
    f16* __restrict__ Wkth, f16* __restrict__ Wktl, f16* __restrict__ Wvt)
{
  int d = blockIdx.x;
  for (int c = threadIdx.x; c < DD; c += 256) {
    float q = Wq[(size_t)c * DD + d];
    float k = Wk[(size_t)c * DD + d];
    float v = Wv[(size_t)c * DD + d];
    f16 qh = (f16)q, kh = (f16)k;
    size_t o = (size_t)d * DD + c;
    Wqth[o] = qh; Wqtl[o] = (f16)(q - (float)qh);
    Wkth[o] = kh; Wktl[o] = (f16)(k - (float)kh);
    Wvt[o]  = (f16)v;
  }
}

// ---------------- K3: FUSED Q+K projection (split x split, 3-term, 2 B-phases) -----
// X tile staged once; Wq phase then Wk phase re-staged into the same B buffers.
__global__ __launch_bounds__(256, 2) void k_projqk(
    const f16* __restrict__ Xhi, const f16* __restrict__ Xlo,
    const f16* __restrict__ Wqth, const f16* __restrict__ Wqtl,
    const f16* __restrict__ Wkth, const f16* __restrict__ Wktl,
    f16* __restrict__ Qhi, f16* __restrict__ Qlo,
    f16* __restrict__ Khi, f16* __restrict__ Klo)
{
  __shared__ __align__(16) char Ah[16384], Al[16384], Bh[16384], Bl[16384];
  int tid = threadIdx.x, wv = tid >> 6, ln = tid & 63;
  int mw = wv & 1, nw = wv >> 1;
  int n0 = blockIdx.x * 128;   // d
  int m0 = blockIdx.y * 128;   // s
  f32x4 acc[2][4][4];
  #pragma unroll
  for (int p = 0; p < 2; p++)
    #pragma unroll
    for (int i = 0; i < 4; i++)
      #pragma unroll
      for (int j = 0; j < 4; j++) acc[p][i][j] = (f32x4)(0.0f);
  int quad = ln >> 4, l15 = ln & 15;
  for (int k0 = 0; k0 < DD; k0 += 64) {
    __syncthreads();
    stage128((const char*)(Xhi  + (size_t)m0 * DD + k0), 1024, Ah, wv, ln);
    stage128((const char*)(Xlo  + (size_t)m0 * DD + k0), 1024, Al, wv, ln);
    stage128((const char*)(Wqth + (size_t)n0 * DD + k0), 1024, Bh, wv, ln);
    stage128((const char*)(Wqtl + (size_t)n0 * DD + k0), 1024, Bl, wv, ln);
    __syncthreads();
    #pragma unroll
    for (int ks = 0; ks < 2; ks++) {
      int kc = ks * 4 + quad;
      half8 ah[4], al[4], bh[4], bl[4];
      #pragma unroll
      for (int t = 0; t < 4; t++) {
        ah[t] = frag_ld(Ah, mw * 64 + t * 16 + l15, kc);
        al[t] = frag_ld(Al, mw * 64 + t * 16 + l15, kc);
        bh[t] = frag_ld(Bh, nw * 64 + t * 16 + l15, kc);
        bl[t] = frag_ld(Bl, nw * 64 + t * 16 + l15, kc);
      }
      #pragma unroll
      for (int i = 0; i < 4; i++)
        #pragma unroll
        for (int j = 0; j < 4; j++) {
          acc[0][i][j] = MF(ah[i], bh[j], acc[0][i][j]);
          acc[0][i][j] = MF(ah[i], bl[j], acc[0][i][j]);
          acc[0][i][j] = MF(al[i], bh[j], acc[0][i][j]);
        }
    }
    __syncthreads();
    stage128((const char*)(Wkth + (size_t)n0 * DD + k0), 1024, Bh, wv, ln);
    stage128((const char*)(Wktl + (size_t)n0 * DD + k0), 1024, Bl, wv, ln);
    __syncthreads();
    #pragma unroll
    for (int ks = 0; ks < 2; ks++) {
      int kc = ks * 4 + quad;
      half8 ah[4], al[4], bh[4], bl[4];
      #pragma unroll
      for (int t = 0; t < 4; t++) {
        ah[t] = frag_ld(Ah, mw * 64 + t * 16 + l15, kc);
        al[t] = frag_ld(Al, mw * 64 + t * 16 + l15, kc);
        bh[t] = frag_ld(Bh, nw * 64 + t * 16 + l15, kc);
        bl[t] = frag_ld(Bl, nw * 64 + t * 16 + l15, kc);
      }
      #pragma unroll
      for (int i = 0; i < 4; i++)
        #pragma unroll
        for (int j = 0; j < 4; j++) {
          acc[1][i][j] = MF(ah[i], bh[j], acc[1][i][j]);
          acc[1][i][j] = MF(ah[i], bl[j], acc[1][i][j]);
          acc[1][i][j] = MF(al[i], bh[j], acc[1][i][j]);
        }
    }
  }
  #pragma unroll
  for (int i = 0; i < 4; i++)
    #pragma unroll
    for (int j = 0; j < 4; j++)
      #pragma unroll
      for (int rg = 0; rg < 4; rg++) {
        int gm = m0 + mw * 64 + i * 16 + quad * 4 + rg;
        int gn = n0 + nw * 64 + j * 16 + l15;
        size_t o = (size_t)gm * DD + gn;
        float vq = acc[0][i][j][rg];
        f16 hq = (f16)vq;
        Qhi[o] = hq; Qlo[o] = (f16)(vq - (float)hq);
        float vk = acc[1][i][j][rg];
        f16 hk = (f16)vk;
        Khi[o] = hk; Klo[o] = (f16)(vk - (float)hk);
      }
}

// ---------------- K4: Vt GEMM (plain fp16): Vt[d][s] ----------------
__global__ __launch_bounds__(256, 2) void k_vt(
    const f16* __restrict__ Wvt, const f16* __restrict__ Xhi, f16* __restrict__ Vt)
{
  __shared__ __align__(16) char Ah[16384], Bh[16384];
  int tid = threadIdx.x, wv = tid >> 6, ln = tid & 63;
  int mw = wv & 1, nw = wv >> 1;
  int n0 = blockIdx.x * 128;   // s
  int m0 = blockIdx.y * 128;   // d
  f32x4 acc[4][4];
  #pragma unroll
  for (int i = 0; i < 4; i++)
    #pragma unroll
    for (int j = 0; j < 4; j++) acc[i][j] = (f32x4)(0.0f);
  for (int k0 = 0; k0 < DD; k0 += 64) {
    __syncthreads();
    stage128((const char*)(Wvt + (size_t)m0 * DD + k0), 1024, Ah, wv, ln);
    stage128((const char*)(Xhi + (size_t)n0 * DD + k0), 1024, Bh, wv, ln);
    __syncthreads();
    int quad = ln >> 4, l15 = ln & 15;
    #pragma unroll
    for (int ks = 0; ks < 2; ks++) {
      int kc = ks * 4 + quad;
      half8 a[4], b[4];
      #pragma unroll
      for (int t = 0; t < 4; t++) {
        a[t] = frag_ld(Ah, mw * 64 + t * 16 + l15, kc);
        b[t] = frag_ld(Bh, nw * 64 + t * 16 + l15, kc);
      }
      #pragma unroll
      for (int i = 0; i < 4; i++)
        #pragma unroll
        for (int j = 0; j < 4; j++) acc[i][j] = MF(a[i], b[j], acc[i][j]);
    }
  }
  int quad = ln >> 4, l15 = ln & 15;
  #pragma unroll
  for (int i = 0; i < 4; i++)
    #pragma unroll
    for (int j = 0; j < 4; j++)
      #pragma unroll
      for (int rg = 0; rg < 4; rg++) {
        int gm = m0 + mw * 64 + i * 16 + quad * 4 + rg;   // d
        int gn = n0 + nw * 64 + j * 16 + l15;             // s
        Vt[(size_t)gm * NR + gn] = (f16)acc[i][j][rg];
      }
}

// ---------------- K5: S = Q K^T / sqrt(D) — 64q x 256k blocks, 2 key phases -------
__global__ __launch_bounds__(256, 2) void k_qk(
    const f16* __restrict__ Qhi, const f16* __restrict__ Qlo,
    const f16* __restrict__ Khi, const f16* __restrict__ Klo,
    float* __restrict__ S, int chunk)
{
  __shared__ __align__(16) char Ah[8192], Al[8192], Bh[16384], Bl[16384];
  int tid = threadIdx.x, wv = tid >> 6, ln = tid & 63;
  int n0 = blockIdx.x * 256;          // key base
  int m0 = blockIdx.y * 64;           // query base
  int z  = blockIdx.z;                // batch within chunk
  size_t brow = ((size_t)chunk * 8 + z) * SS;
  f32x4 acc[2][4][2];
  #pragma unroll
  for (int p = 0; p < 2; p++)
    #pragma unroll
    for (int i = 0; i < 4; i++)
      #pragma unroll
      for (int j = 0; j < 2; j++) acc[p][i][j] = (f32x4)(0.0f);
  int quad = ln >> 4, l15 = ln & 15;
  for (int k0 = 0; k0 < DD; k0 += 64) {
    __syncthreads();
    stage64 ((const char*)(Qhi + (brow + m0) * DD + k0), 1024, Ah, wv, ln);
    stage64 ((const char*)(Qlo + (brow + m0) * DD + k0), 1024, Al, wv, ln);
    stage128((const char*)(Khi + (brow + n0) * DD + k0), 1024, Bh, wv, ln);
    stage128((const char*)(Klo + (brow + n0) * DD + k0), 1024, Bl, wv, ln);
    __syncthreads();
    #pragma unroll
    for (int ks = 0; ks < 2; ks++) {
      int kc = ks * 4 + quad;
      half8 ah[4], al[4], bh[2], bl[2];
      #pragma unroll
      for (int t = 0; t < 4; t++) {
        ah[t] = frag_ld(Ah, t * 16 + l15, kc);
        al[t] = frag_ld(Al, t * 16 + l15, kc);
      }
      #pragma unroll
      for (int t = 0; t < 2; t++) {
        bh[t] = frag_ld(Bh, wv * 32 + t * 16 + l15, kc);
        bl[t] = frag_ld(Bl, wv * 32 + t * 16 + l15, kc);
      }
      #pragma unroll
      for (int i = 0; i < 4; i++)
        #pragma unroll
        for (int j = 0; j < 2; j++) {
          acc[0][i][j] = MF(ah[i], bh[j], acc[0][i][j]);
          acc[0][i][j] = MF(ah[i], bl[j], acc[0][i][j]);
          acc[0][i][j] = MF(al[i], bh[j], acc[0][i][j]);
        }
    }
    __syncthreads();
    stage128((const char*)(Khi + (brow + n0 + 128) * DD + k0), 1024, Bh, wv, ln);
    stage128((const char*)(Klo + (brow + n0 + 128) * DD + k0), 1024, Bl, wv, ln);
    __syncthreads();
    #pragma unroll
    for (int ks = 0; ks < 2; ks++) {
      int kc = ks * 4 + quad;
      half8 ah[4], al[4], bh[2], bl[2];
      #pragma unroll
      for (int t = 0; t < 4; t++) {
        ah[t] = frag_ld(Ah, t * 16 + l15, kc);
        al[t] = frag_ld(Al, t * 16 + l15, kc);
      }
      #pragma unroll
      for (int t = 0; t < 2; t++) {
        bh[t] = frag_ld(Bh, wv * 32 + t * 16 + l15, kc);
        bl[t] = frag_ld(Bl, wv * 32 + t * 16 + l15, kc);
      }
      #pragma unroll
      for (int i = 0; i < 4; i++)
        #pragma unroll
        for (int j = 0; j < 2; j++) {
          acc[1][i][j] = MF(ah[i], bh[j], acc[1][i][j]);
          acc[1][i][j] = MF(ah[i], bl[j], acc[1][i][j]);
          acc[1][i][j] = MF(al[i], bh[j], acc[1][i][j]);
        }
    }
  }
  const float scale = 0.044194173824159216f;   // 1/sqrt(512)
  #pragma unroll
  for (int p = 0; p < 2; p++)
    #pragma unroll
    for (int i = 0; i < 4; i++)
      #pragma unroll
      for (int j = 0; j < 2; j++)
        #pragma unroll
        for (int rg = 0; rg < 4; rg++) {
          int gm = m0 + i * 16 + quad * 4 + rg;
          int gn = n0 + p * 128 + wv * 32 + j * 16 + l15;
          S[((size_t)z * SS + gm) * SS + gn] = acc[p][i][j][rg] * scale;
        }
}

// ---------------- K6: row softmax S(fp32) -> P(fp16) ----------------
__global__ __launch_bounds__(256) void k_softmax(
    const float* __restrict__ S, char* __restrict__ Pb, int chunk)
{
  int rc = blockIdx.x;
  int tid = threadIdx.x;
  const float* row = S + (size_t)rc * SS;
  float4 v = ((const float4*)row)[tid];
  float mx = fmaxf(fmaxf(v.x, v.y), fmaxf(v.z, v.w));
  #pragma unroll
  for (int off = 32; off > 0; off >>= 1) mx = fmaxf(mx, __shfl_xor(mx, off, 64));
  __shared__ float red[10];
  int wv = tid >> 6;
  if ((tid & 63) == 0) red[wv] = mx;
  __syncthreads();
  if (tid == 0) red[8] = fmaxf(fmaxf(red[0], red[1]), fmaxf(red[2], red[3]));
  __syncthreads();
  mx = red[8];
  float e0 = __expf(v.x - mx), e1 = __expf(v.y - mx);
  float e2 = __expf(v.z - mx), e3 = __expf(v.w - mx);
  float sm = e0 + e1 + e2 + e3;
  #pragma unroll
  for (int off = 32; off > 0; off >>= 1) sm += __shfl_xor(sm, off, 64);
  if ((tid & 63) == 0) red[4 + wv] = sm;
  __syncthreads();
  if (tid == 0) red[9] = red[4] + red[5] + red[6] + red[7];
  __syncthreads();
  float inv = 1.0f / red[9];
  int grow = chunk * 8192 + rc;
  char* pb = Pb + p_row_off(grow);
  ((h4*)pb)[tid] = (h4){(f16)(e0 * inv), (f16)(e1 * inv), (f16)(e2 * inv), (f16)(e3 * inv)};
}

// ---------------- K7: O = P V  (plain fp16 MFMA) ----------------
__global__ __launch_bounds__(256, 2) void k_pv(
    const char* __restrict__ Pb, const f16* __restrict__ Vt, float* __restrict__ O)
{
  __shared__ __align__(16) char Ah[16384], Bh[16384];
  int tid = threadIdx.x, wv = tid >> 6, ln = tid & 63;
  int mw = wv & 1, nw = wv >> 1;
  int n0 = blockIdx.x * 128;          // d_out
  int m0 = blockIdx.y * 128;          // query (within batch)
  int b  = blockIdx.z;
  int grow = b * SS + m0;
  const char* Pt = Pb + p_row_off(grow);
  f32x4 acc[4][4];
  #pragma unroll
  for (int i = 0; i < 4; i++)
    #pragma unroll
    for (int j = 0; j < 4; j++) acc[i][j] = (f32x4)(0.0f);
  for (int k0 = 0; k0 < SS; k0 += 64) {
    __syncthreads();
    stage128(Pt + k0 * 2, 2048, Ah, wv, ln);
    stage128((const char*)(Vt + (size_t)n0 * NR + (size_t)b * SS + k0), NR * 2, Bh, wv, ln);
    __syncthreads();
    int quad = ln >> 4, l15 = ln & 15;
    #pragma unroll
    for (int ks = 0; ks < 2; ks++) {
      int kc = ks * 4 + quad;
      half8 a[4], bf[4];
      #pragma unroll
      for (int t = 0; t < 4; t++) {
        a[t]  = frag_ld(Ah, mw * 64 + t * 16 + l15, kc);
        bf[t] = frag_ld(Bh, nw * 64 + t * 16 + l15, kc);
      }
      #pragma unroll
      for (int i = 0; i < 4; i++)
        #pragma unroll
        for (int j = 0; j < 4; j++) acc[i][j] = MF(a[i], bf[j], acc[i][j]);
    }
  }
  int quad = ln >> 4, l15 = ln & 15;
  #pragma unroll
  for (int i = 0; i < 4; i++)
    #pragma unroll
    for (int j = 0; j < 4; j++)
      #pragma unroll
      for (int rg = 0; rg < 4; rg++) {
        int gm = m0 + mw * 64 + i * 16 + quad * 4 + rg;
        int gn = n0 + nw * 64 + j * 16 + l15;
        O[((size_t)b * SS + gm) * DD + gn] = acc[i][j][rg];
      }
}

extern "C" void kernel_launch(void* const* d_in, const int* in_sizes, int n_in,
                              void* d_out, int out_size, void* d_ws, size_t ws_size,
                              hipStream_t stream) {
  const int*   inp   = (const int*)d_in[0];
  const float* wemb  = (const float*)d_in[1];
  const float* pemb  = (const float*)d_in[2];
  const float* gamma = (const float*)d_in[3];
  const float* beta  = (const float*)d_in[4];
  const float* Wk    = (const float*)d_in[5];
  const float* Wq    = (const float*)d_in[6];
  const float* Wv    = (const float*)d_in[7];

  // ws (192 MiB): [Xhi 32M][Xlo 32M][Qhi 32M][Qlo 32M][Khi 32M][Klo 32M]
  // overlays: Sbuf(32M)->Xhi after k_vt; Vt(32M)->Xlo after k_projqk; P(64M)->Q rows
  char* ws = (char*)d_ws;
  f16* Xhi = (f16*)ws;
  f16* Xlo = (f16*)(ws + ((size_t)32 << 20));
  f16* Qhi = (f16*)(ws + ((size_t)64 << 20));
  f16* Qlo = (f16*)(ws + ((size_t)96 << 20));
  f16* Khi = (f16*)(ws + ((size_t)128 << 20));
  f16* Klo = (f16*)(ws + ((size_t)160 << 20));
  float* Sbuf = (float*)ws;                       // over Xhi (dead after k_vt)
  f16* Vt  = (f16*)(ws + ((size_t)32 << 20));     // over Xlo (dead after k_projqk)
  char* Pb = ws + ((size_t)64 << 20);             // over Q rows, chunk-interleaved

  f16* Wqth = (f16*)d_out;                        // weights parked in d_out head
  f16* Wqtl = Wqth + (size_t)DD * DD;
  f16* Wkth = Wqtl + (size_t)DD * DD;
  f16* Wktl = Wkth + (size_t)DD * DD;
  f16* Wvt  = Wktl + (size_t)DD * DD;

  k_embed_ln<<<NR, 256, 0, stream>>>(inp, wemb, pemb, gamma, beta, Xhi, Xlo);
  k_prep_w<<<DD, 256, 0, stream>>>(Wq, Wk, Wv, Wqth, Wqtl, Wkth, Wktl, Wvt);
  k_projqk<<<dim3(DD / 128, NR / 128), 256, 0, stream>>>(
      Xhi, Xlo, Wqth, Wqtl, Wkth, Wktl, Qhi, Qlo, Khi, Klo);
  k_vt<<<dim3(NR / 128, DD / 128), 256, 0, stream>>>(Wvt, Xhi, Vt);
  for (int c = 0; c < 4; c++) {
    k_qk<<<dim3(SS / 256, SS / 64, 8), 256, 0, stream>>>(Qhi, Qlo, Khi, Klo, Sbuf, c);
    k_softmax<<<8192, 256, 0, stream>>>(Sbuf, Pb, c);
  }
  k_pv<<<dim3(DD / 128, SS / 128, BB), 256, 0, stream>>>(Pb, Vt, (float*)d_out);
}